// Round 1
// 131.779 us; speedup vs baseline: 1.0061x; 1.0061x over previous
//
#include <hip/hip_runtime.h>

// CrumbReconstructor R4: codebook rows via scalar (SGPR) broadcast loads.
//
// R3 counters: VALUBusy ~101-107% — the gfx94x-derived formula double-counts
// on gfx950's SIMD-32, so real VALU busy is ~50%; the other ~50% is ds_read
// latency stall (1-row-deep prefetch, 37% occupancy). MfmaUtil 0, HBM 6.7%.
//
// Fix: rows are wave-uniform -> fetch with s_load into SGPRs (v_fma takes one
// SGPR operand for free). Kills all per-row LDS reads, LDS address VALU, and
// the ra/rb/rn rotation movs; row data stops costing VGPRs. Norms stay in LDS
// (no float SALU exists) read as one broadcast float4 per 4 rows.
//
// CHUNK=8 rows per s_load batch, single-buffered: SMEM returns are unordered
// so any wait is lgkmcnt(0) — one drain per ~224cy of compute (R2 drained per
// ROW, which is why it stalled). Residual drain hidden by ~6 waves/SIMD.
// BLOCK=128 doubles block count (12.25/CU) vs R3's 6.1 to lift occupancy.
//
// Hot-loop math bit-identical to R3 (absmax was 0.0): sequential fmaf dot,
// fmaf(dot,-2,knorm)+rn, strict < (first/lowest index wins exact ties).

#define LBLK 8      // memblock length
#define NROW 256    // codebook rows
#define TPK 2       // key-blocks per thread
#define BLOCK 128   // threads per workgroup
#define CHUNK 8     // rows per scalar-load batch

__global__ __launch_bounds__(BLOCK, 2) void crumb_kernel(
    const float* __restrict__ x,
    const float* __restrict__ mem,
    float* __restrict__ out,
    int nblocks)
{
    __shared__ float s_mem[NROW * LBLK];   // 8 KB, rows contiguous (gather)
    __shared__ float s_norm[NROW];         // 1 KB (hot-loop norms)

    const int tid = threadIdx.x;

    // --- stage codebook rows + norms into LDS (2 rows per thread) ---
    {
        const float4* g = (const float4*)mem;
        #pragma unroll
        for (int rr = tid; rr < NROW; rr += BLOCK) {
            float4 a = g[rr * 2 + 0];
            float4 b = g[rr * 2 + 1];
            ((float4*)s_mem)[rr * 2 + 0] = a;
            ((float4*)s_mem)[rr * 2 + 1] = b;
            float q0 = a.x * a.x, q1 = a.y * a.y, q2 = a.z * a.z, q3 = a.w * a.w;
            float q4 = b.x * b.x, q5 = b.y * b.y, q6 = b.z * b.z, q7 = b.w * b.w;
            s_norm[rr] = ((q0 + q1) + (q2 + q3)) + ((q4 + q5) + (q6 + q7));
        }
    }
    __syncthreads();

    const long base = (long)blockIdx.x * (BLOCK * TPK) + tid;

    float k[TPK][LBLK];
    float knorm[TPK];
    long  kb[TPK];
    bool  valid[TPK];

    #pragma unroll
    for (int t = 0; t < TPK; ++t) {
        long b0 = base + (long)t * BLOCK;
        valid[t] = (b0 < (long)nblocks);
        kb[t] = valid[t] ? b0 : 0;
        const float4* g = (const float4*)(x + kb[t] * LBLK);
        float4 a = g[0], b = g[1];
        k[t][0] = a.x; k[t][1] = a.y; k[t][2] = a.z; k[t][3] = a.w;
        k[t][4] = b.x; k[t][5] = b.y; k[t][6] = b.z; k[t][7] = b.w;
        float q0 = a.x * a.x, q1 = a.y * a.y, q2 = a.z * a.z, q3 = a.w * a.w;
        float q4 = b.x * b.x, q5 = b.y * b.y, q6 = b.z * b.z, q7 = b.w * b.w;
        knorm[t] = ((q0 + q1) + (q2 + q3)) + ((q4 + q5) + (q6 + q7));
    }

    float best[TPK];
    int   bidx[TPK];
    #pragma unroll
    for (int t = 0; t < TPK; ++t) { best[t] = 3.4e38f; bidx[t] = 0; }

    // --- preload chunk 0: rows via uniform scalar loads, norms via LDS ---
    float r[CHUNK][LBLK];    // wave-uniform -> SGPRs
    float rnv[CHUNK];
    #pragma unroll
    for (int i = 0; i < CHUNK; ++i) {
        #pragma unroll
        for (int j = 0; j < LBLK; ++j) r[i][j] = mem[i * LBLK + j];
    }
    {
        float4 tA = *(const float4*)&s_norm[0];
        float4 tB = *(const float4*)&s_norm[4];
        rnv[0] = tA.x; rnv[1] = tA.y; rnv[2] = tA.z; rnv[3] = tA.w;
        rnv[4] = tB.x; rnv[5] = tB.y; rnv[6] = tB.z; rnv[7] = tB.w;
    }

    #pragma unroll 2
    for (int m = 0; m < NROW; m += CHUNK) {
        // score current chunk — all operands already in registers, no waits
        #pragma unroll
        for (int i = 0; i < CHUNK; ++i) {
            #pragma unroll
            for (int t = 0; t < TPK; ++t) {
                float dot = k[t][0] * r[i][0];
                dot = fmaf(k[t][1], r[i][1], dot);
                dot = fmaf(k[t][2], r[i][2], dot);
                dot = fmaf(k[t][3], r[i][3], dot);
                dot = fmaf(k[t][4], r[i][4], dot);
                dot = fmaf(k[t][5], r[i][5], dot);
                dot = fmaf(k[t][6], r[i][6], dot);
                dot = fmaf(k[t][7], r[i][7], dot);
                float d = fmaf(dot, -2.0f, knorm[t]) + rnv[i];
                // strict < : first (lowest) index wins exact ties (= argmin)
                if (d < best[t]) { best[t] = d; bidx[t] = m + i; }
            }
        }
        // prefetch next chunk (wraps to row 0 on last iteration; unused)
        const int mn = (m + CHUNK) & (NROW - 1);
        #pragma unroll
        for (int i = 0; i < CHUNK; ++i) {
            #pragma unroll
            for (int j = 0; j < LBLK; ++j) r[i][j] = mem[(mn + i) * LBLK + j];
        }
        {
            float4 tA = *(const float4*)&s_norm[mn];
            float4 tB = *(const float4*)&s_norm[mn + 4];
            rnv[0] = tA.x; rnv[1] = tA.y; rnv[2] = tA.z; rnv[3] = tA.w;
            rnv[4] = tB.x; rnv[5] = tB.y; rnv[6] = tB.z; rnv[7] = tB.w;
        }
    }

    // --- gather winning rows from LDS, store ---
    #pragma unroll
    for (int t = 0; t < TPK; ++t) {
        if (valid[t]) {
            float4* o = (float4*)(out + kb[t] * LBLK);
            o[0] = ((const float4*)s_mem)[bidx[t] * 2 + 0];
            o[1] = ((const float4*)s_mem)[bidx[t] * 2 + 1];
        }
    }
}

extern "C" void kernel_launch(void* const* d_in, const int* in_sizes, int n_in,
                              void* d_out, int out_size, void* d_ws, size_t ws_size,
                              hipStream_t stream) {
    const float* x   = (const float*)d_in[0];
    const float* mem = (const float*)d_in[1];
    float* out = (float*)d_out;

    int n = in_sizes[0];            // total x elements
    int nblocks = n / LBLK;         // key-blocks
    int grid = (nblocks + BLOCK * TPK - 1) / (BLOCK * TPK);

    hipLaunchKernelGGL(crumb_kernel, dim3(grid), dim3(BLOCK), 0, stream,
                       x, mem, out, nblocks);
}